// Round 4
// baseline (152.625 us; speedup 1.0000x reference)
//
#include <hip/hip_runtime.h>

// MonarchLinear: x[16384,256] fp32, L[68,68,68], R[68,68,68], bias[4608] -> out[16384,4608] fp32.
// Only blocks k=0..3 of the padded (4624) input are nonzero:
//   t1[b,r,l] = sum_p x[b, r*68+p] * L[r,l,p]           (r<4; r==3 only p<52 valid)
//   out[b, s*68+l] = sum_{r<4} t1[b,r,l] * R[l,s,r] + bias[s*68+l]
// Write-bound: 302 MB output (~45 us floor at 6.9 TB/s measured fill BW).
//
// Round 4: REMOVED __builtin_nontemporal_store (round-3 counters: WRITE_SIZE ideal
// at 312 MB but hbm_gbps only 1787 = 22% peak; fill kernel hits 6900. Theory: nt
// bypasses L2 write-coalescing -> 16B-granular HBM bursts = ~1/4 efficiency).

typedef float f4 __attribute__((ext_vector_type(4)));

namespace {
constexpr int MM     = 68;        // Monarch block size
constexpr int IN_D   = 256;
constexpr int OUT_D  = 4608;
constexpr int T_TILE = 16;        // tokens per block
constexpr int NTH    = 256;       // threads per block (4 waves)
constexpr int NJ     = 5;         // s-chunks per thread (last partial)
}

__global__ __launch_bounds__(NTH, 2)
void monarch_fused(const float* __restrict__ x, const float* __restrict__ L,
                   const float* __restrict__ R, const float* __restrict__ bias,
                   float* __restrict__ out)
{
  __shared__ float t1s[T_TILE * 4 * MM];   // [t][r*68 + l], 17408 B
  const int tid = threadIdx.x;
  const long tb = (long)blockIdx.x * T_TILE;

  // ---- per-thread output columns: l4 fixed, s = g + 15j ----
  const int g  = tid / 17;
  const int m  = tid - g * 17;             // 0..16
  const int l4 = 4 * m;

  f4 Rr[NJ][4];                            // R[l4+q][s_j][0..3]
  f4 br[NJ];
  int scol[NJ];
  bool act[NJ];
#pragma unroll
  for (int j = 0; j < NJ; ++j) {
    int s = g + 15 * j;
    // tid==255 (g==15) would duplicate s of g==0; s==67 row only has 52 cols (m<13)
    act[j]  = (tid < 255) && (s < MM) && (s < MM - 1 || m < 13);
    scol[j] = s * MM + l4;
    if (act[j]) {
      br[j] = *(const f4*)(bias + scol[j]);
#pragma unroll
      for (int q = 0; q < 4; ++q)
        Rr[j][q] = *(const f4*)(R + (size_t)(l4 + q) * (MM * MM) + (size_t)s * MM);
    }
  }

  // ---- stage 1: t1[r*68+l] for 16 tokens; x/L broadcast loads from global (L1-hot) ----
  for (int idx = tid; idx < 4 * MM; idx += NTH) {   // 272 tasks: round 2 has tid<16
    const int r = idx / MM;                          // 0..3
    const float* Lp = L + (size_t)idx * MM;          // L[r][l][*] contiguous
    const float* xp = x + tb * IN_D + r * MM;
    const int p4max = (r == 3) ? (IN_D - 3 * MM) / 4 : MM / 4;   // 13 or 17
    float acc[T_TILE];
#pragma unroll
    for (int t = 0; t < T_TILE; ++t) acc[t] = 0.f;
    for (int p4 = 0; p4 < p4max; ++p4) {
      f4 Lv = *(const f4*)(Lp + p4 * 4);
#pragma unroll
      for (int t = 0; t < T_TILE; ++t) {
        f4 xv = *(const f4*)(xp + (size_t)t * IN_D + p4 * 4);  // same addr across lanes in r-group
        acc[t] = fmaf(Lv.x, xv.x, acc[t]);
        acc[t] = fmaf(Lv.y, xv.y, acc[t]);
        acc[t] = fmaf(Lv.z, xv.z, acc[t]);
        acc[t] = fmaf(Lv.w, xv.w, acc[t]);
      }
    }
#pragma unroll
    for (int t = 0; t < T_TILE; ++t) t1s[t * (4 * MM) + idx] = acc[t];
  }
  __syncthreads();

  // ---- stage 2: per token, load t1[r][l4..l4+3] once, emit 5 s-chunks ----
#pragma unroll 2
  for (int t = 0; t < T_TILE; ++t) {
    const float* t1p = t1s + t * (4 * MM) + l4;
    f4 a0 = *(const f4*)(t1p);                 // ds_read_b128, offsets 0/272/544/816 B
    f4 a1 = *(const f4*)(t1p + MM);
    f4 a2 = *(const f4*)(t1p + 2 * MM);
    f4 a3 = *(const f4*)(t1p + 3 * MM);
    float* op = out + (tb + t) * OUT_D;
#pragma unroll
    for (int j = 0; j < NJ; ++j) {
      if (act[j]) {
        f4 o;
#pragma unroll
        for (int q = 0; q < 4; ++q) {
          float oq = br[j][q];
          oq = fmaf(a0[q], Rr[j][q].x, oq);
          oq = fmaf(a1[q], Rr[j][q].y, oq);
          oq = fmaf(a2[q], Rr[j][q].z, oq);
          oq = fmaf(a3[q], Rr[j][q].w, oq);
          o[q] = oq;
        }
        *(f4*)(op + scol[j]) = o;              // plain store: coalesce in L2
      }
    }
  }
}

extern "C" void kernel_launch(void* const* d_in, const int* in_sizes, int n_in,
                              void* d_out, int out_size, void* d_ws, size_t ws_size,
                              hipStream_t stream) {
  const float* x    = (const float*)d_in[0];
  const float* L    = (const float*)d_in[1];
  const float* R    = (const float*)d_in[2];
  const float* bias = (const float*)d_in[3];
  float* out = (float*)d_out;

  const int ntok = in_sizes[0] / IN_D;       // 16384
  dim3 grid(ntok / T_TILE);                  // 1024 blocks x 256 threads
  monarch_fused<<<grid, NTH, 0, stream>>>(x, L, R, bias, out);
}

// Round 5
// 137.954 us; speedup vs baseline: 1.1063x; 1.1063x over previous
//
#include <hip/hip_runtime.h>

// MonarchLinear: x[16384,256] fp32, L[68,68,68], R[68,68,68], bias[4608] -> out[16384,4608] fp32.
//   t1[b,r,l] = sum_p x[b, r*68+p] * L[r,l,p]           (r<4; r==3 only p<52 valid)
//   out[b, s*68+l] = sum_{r<4} t1[b,r,l] * R[l,s,r] + bias[s*68+l]
//
// Round 5: SPLIT into stage1 (x@L -> t1 in ws, 17.8MB) and stage2 (t1@R -> out).
// Rounds 1-4 all landed 134-153us regardless of store flavor/mapping while the
// write roofline is ~50us -> the fused structure (occupancy 2/CU, stage-1 work +
// barrier in front of the store drain) is the suspect. Stage2 is now a pure
// streaming kernel: LDS-stage 16 t1 rows, FMA, contiguous 1KB/instr stores.

typedef float f4 __attribute__((ext_vector_type(4)));

namespace {
constexpr int MM     = 68;
constexpr int IN_D   = 256;
constexpr int OUT_D  = 4608;
constexpr int T_TILE = 16;        // tokens per block (both stages)
constexpr int NTH    = 256;
constexpr int NJ     = 5;         // s-chunks per thread in stage 2
constexpr int T1W    = 4 * MM;    // 272 floats per token in t1
}

// ---------------- stage 1: t1[b][r*68+l] ----------------
__global__ __launch_bounds__(NTH, 6)
void monarch_stage1(const float* __restrict__ x, const float* __restrict__ L,
                    float* __restrict__ t1ws)
{
  __shared__ float t1s[T_TILE * T1W];
  const int tid = threadIdx.x;
  const long tb = (long)blockIdx.x * T_TILE;

  for (int idx = tid; idx < T1W; idx += NTH) {      // 272 tasks
    const int r = idx / MM;
    const float* Lp = L + (size_t)idx * MM;
    const float* xp = x + tb * IN_D + r * MM;
    const int p4max = (r == 3) ? (IN_D - 3 * MM) / 4 : MM / 4;   // 13 or 17
    float acc[T_TILE];
#pragma unroll
    for (int t = 0; t < T_TILE; ++t) acc[t] = 0.f;
    for (int p4 = 0; p4 < p4max; ++p4) {
      f4 Lv = *(const f4*)(Lp + p4 * 4);
#pragma unroll
      for (int t = 0; t < T_TILE; ++t) {
        f4 xv = *(const f4*)(xp + (size_t)t * IN_D + p4 * 4);
        acc[t] = fmaf(Lv.x, xv.x, acc[t]);
        acc[t] = fmaf(Lv.y, xv.y, acc[t]);
        acc[t] = fmaf(Lv.z, xv.z, acc[t]);
        acc[t] = fmaf(Lv.w, xv.w, acc[t]);
      }
    }
#pragma unroll
    for (int t = 0; t < T_TILE; ++t) t1s[t * T1W + idx] = acc[t];
  }
  __syncthreads();
  // linear copy LDS -> ws ([token][272] layout matches LDS tile exactly)
  float* wp = t1ws + tb * T1W;
#pragma unroll
  for (int k = 0; k < (T_TILE * T1W) / NTH; ++k)    // 17 contiguous sweeps
    wp[tid + k * NTH] = t1s[tid + k * NTH];
}

// ---------------- stage 2: out = t1 @ R + bias (pure stream) ----------------
__global__ __launch_bounds__(NTH, 3)
void monarch_stage2(const float* __restrict__ t1ws, const float* __restrict__ R,
                    const float* __restrict__ bias, float* __restrict__ out)
{
  __shared__ float t1s[T_TILE * T1W];
  const int tid = threadIdx.x;
  const long tb = (long)blockIdx.x * T_TILE;

  // per-thread output columns: l4 fixed, s = g + 15j  (byte off = 16*tid + 4080*j)
  const int g  = tid / 17;
  const int m  = tid - g * 17;
  const int l4 = 4 * m;

  f4 Rr[NJ][4];
  f4 br[NJ];
  int scol[NJ];
  bool act[NJ];
#pragma unroll
  for (int j = 0; j < NJ; ++j) {
    int s = g + 15 * j;
    act[j]  = (tid < 255) && (s < MM) && (s < MM - 1 || m < 13);  // 4608 = 67*68+52
    scol[j] = s * MM + l4;
    if (act[j]) {
      br[j] = *(const f4*)(bias + scol[j]);
#pragma unroll
      for (int q = 0; q < 4; ++q)
        Rr[j][q] = *(const f4*)(R + (size_t)(l4 + q) * (MM * MM) + (size_t)s * MM);
    }
  }

  // stage t1 tile (4352 floats, 17 contiguous sweeps)
  const float* rp = t1ws + tb * T1W;
#pragma unroll
  for (int k = 0; k < (T_TILE * T1W) / NTH; ++k)
    t1s[tid + k * NTH] = rp[tid + k * NTH];
  __syncthreads();

#pragma unroll 2
  for (int t = 0; t < T_TILE; ++t) {
    const float* t1p = t1s + t * T1W + l4;
    f4 a0 = *(const f4*)(t1p);
    f4 a1 = *(const f4*)(t1p + MM);
    f4 a2 = *(const f4*)(t1p + 2 * MM);
    f4 a3 = *(const f4*)(t1p + 3 * MM);
    float* op = out + (tb + t) * OUT_D;
#pragma unroll
    for (int j = 0; j < NJ; ++j) {
      if (act[j]) {
        f4 o;
#pragma unroll
        for (int q = 0; q < 4; ++q) {
          float oq = br[j][q];
          oq = fmaf(a0[q], Rr[j][q].x, oq);
          oq = fmaf(a1[q], Rr[j][q].y, oq);
          oq = fmaf(a2[q], Rr[j][q].z, oq);
          oq = fmaf(a3[q], Rr[j][q].w, oq);
          o[q] = oq;
        }
        *(f4*)(op + scol[j]) = o;
      }
    }
  }
}

// ---------------- fused fallback (round-4 kernel) if ws too small ----------------
__global__ __launch_bounds__(NTH, 2)
void monarch_fused(const float* __restrict__ x, const float* __restrict__ L,
                   const float* __restrict__ R, const float* __restrict__ bias,
                   float* __restrict__ out)
{
  __shared__ float t1s[T_TILE * T1W];
  const int tid = threadIdx.x;
  const long tb = (long)blockIdx.x * T_TILE;
  const int g  = tid / 17;
  const int m  = tid - g * 17;
  const int l4 = 4 * m;
  f4 Rr[NJ][4]; f4 br[NJ]; int scol[NJ]; bool act[NJ];
#pragma unroll
  for (int j = 0; j < NJ; ++j) {
    int s = g + 15 * j;
    act[j]  = (tid < 255) && (s < MM) && (s < MM - 1 || m < 13);
    scol[j] = s * MM + l4;
    if (act[j]) {
      br[j] = *(const f4*)(bias + scol[j]);
#pragma unroll
      for (int q = 0; q < 4; ++q)
        Rr[j][q] = *(const f4*)(R + (size_t)(l4 + q) * (MM * MM) + (size_t)s * MM);
    }
  }
  for (int idx = tid; idx < T1W; idx += NTH) {
    const int r = idx / MM;
    const float* Lp = L + (size_t)idx * MM;
    const float* xp = x + tb * IN_D + r * MM;
    const int p4max = (r == 3) ? (IN_D - 3 * MM) / 4 : MM / 4;
    float acc[T_TILE];
#pragma unroll
    for (int t = 0; t < T_TILE; ++t) acc[t] = 0.f;
    for (int p4 = 0; p4 < p4max; ++p4) {
      f4 Lv = *(const f4*)(Lp + p4 * 4);
#pragma unroll
      for (int t = 0; t < T_TILE; ++t) {
        f4 xv = *(const f4*)(xp + (size_t)t * IN_D + p4 * 4);
        acc[t] = fmaf(Lv.x, xv.x, acc[t]);
        acc[t] = fmaf(Lv.y, xv.y, acc[t]);
        acc[t] = fmaf(Lv.z, xv.z, acc[t]);
        acc[t] = fmaf(Lv.w, xv.w, acc[t]);
      }
    }
#pragma unroll
    for (int t = 0; t < T_TILE; ++t) t1s[t * T1W + idx] = acc[t];
  }
  __syncthreads();
#pragma unroll 2
  for (int t = 0; t < T_TILE; ++t) {
    const float* t1p = t1s + t * T1W + l4;
    f4 a0 = *(const f4*)(t1p);
    f4 a1 = *(const f4*)(t1p + MM);
    f4 a2 = *(const f4*)(t1p + 2 * MM);
    f4 a3 = *(const f4*)(t1p + 3 * MM);
    float* op = out + (tb + t) * OUT_D;
#pragma unroll
    for (int j = 0; j < NJ; ++j) {
      if (act[j]) {
        f4 o;
#pragma unroll
        for (int q = 0; q < 4; ++q) {
          float oq = br[j][q];
          oq = fmaf(a0[q], Rr[j][q].x, oq);
          oq = fmaf(a1[q], Rr[j][q].y, oq);
          oq = fmaf(a2[q], Rr[j][q].z, oq);
          oq = fmaf(a3[q], Rr[j][q].w, oq);
          o[q] = oq;
        }
        *(f4*)(op + scol[j]) = o;
      }
    }
  }
}

extern "C" void kernel_launch(void* const* d_in, const int* in_sizes, int n_in,
                              void* d_out, int out_size, void* d_ws, size_t ws_size,
                              hipStream_t stream) {
  const float* x    = (const float*)d_in[0];
  const float* L    = (const float*)d_in[1];
  const float* R    = (const float*)d_in[2];
  const float* bias = (const float*)d_in[3];
  float* out = (float*)d_out;

  const int ntok   = in_sizes[0] / IN_D;          // 16384
  const int nblk   = ntok / T_TILE;               // 1024
  const size_t t1b = (size_t)ntok * T1W * sizeof(float);  // 17.8 MB

  if (ws_size >= t1b) {
    float* t1ws = (float*)d_ws;
    monarch_stage1<<<nblk, NTH, 0, stream>>>(x, L, t1ws);
    monarch_stage2<<<nblk, NTH, 0, stream>>>(t1ws, R, bias, out);
  } else {
    monarch_fused<<<nblk, NTH, 0, stream>>>(x, L, R, bias, out);
  }
}